// Round 1
// baseline (320.383 us; speedup 1.0000x reference)
//
#include <hip/hip_runtime.h>

typedef __bf16 bf16x8_t __attribute__((ext_vector_type(8)));
typedef float f32x4_t __attribute__((ext_vector_type(4)));
typedef unsigned short u16;

__device__ __forceinline__ u16 f2b(float f) {
  __bf16 h = (__bf16)f;
  u16 u;
  __builtin_memcpy(&u, &h, 2);
  return u;
}
__device__ __forceinline__ float b2f(u16 u) {
  unsigned int i = ((unsigned int)u) << 16;
  float f;
  __builtin_memcpy(&f, &i, 4);
  return f;
}
__device__ __forceinline__ unsigned int shflu(unsigned int v, int s) {
  return (unsigned int)__shfl((int)v, s, 64);
}

union FragU { unsigned int u[4]; bf16x8_t v; };

// ---------------- prep: bias gather -> bf16 [6][343][352] ----------------
__global__ void prep_bias_k(const float* __restrict__ bias_table,
                            const int* __restrict__ rel_index,
                            u16* __restrict__ bias_bf) {
  int i = blockIdx.x * 256 + threadIdx.x;
  if (i >= 6 * 343 * 343) return;
  int h = i / 117649;
  int rem = i - h * 117649;
  int r = rem / 343;
  int c = rem - r * 343;
  int idx = rel_index[rem];
  bias_bf[((size_t)h * 343 + r) * 352 + c] = f2b(bias_table[idx * 6 + h]);
}

// ---------------- prep: mask fp32 -> bf16 [64][343][352] ----------------
__global__ void prep_mask_k(const float* __restrict__ mask, u16* __restrict__ mask_bf) {
  int i = blockIdx.x * 256 + threadIdx.x;
  if (i >= 64 * 343 * 343) return;
  int w = i / 117649;
  int rem = i - w * 117649;
  int r = rem / 343;
  int c = rem - r * 343;
  mask_bf[((size_t)w * 343 + r) * 352 + c] = f2b(mask[i]);
}

// ---------------- prep: weights fp32 -> bf16 ----------------
__global__ void prep_w_k(const float* __restrict__ qkv_w, const float* __restrict__ proj_w,
                         u16* __restrict__ wq, u16* __restrict__ wp) {
  int i = blockIdx.x * 256 + threadIdx.x;
  if (i < 110592) wq[i] = f2b(qkv_w[i]);
  int j = i - 110592;
  if (j >= 0 && j < 36864) wp[j] = f2b(proj_w[j]);
}

// ---------------- QKV GEMM: [87808,192] x [576,192]^T -> q,k,v bf16 [b,h,n,32] ----------------
__global__ __launch_bounds__(256) void qkv_gemm(const float* __restrict__ x,
                                                const u16* __restrict__ w_bf,
                                                const float* __restrict__ qkv_b,
                                                u16* __restrict__ qb,
                                                u16* __restrict__ kb,
                                                u16* __restrict__ vb) {
  __shared__ u16 xs[64][200];   // +8 pad
  __shared__ u16 wsx[64][200];
  const int m0 = blockIdx.x * 64;
  const float* xrow = x + (size_t)m0 * 192;
  // stage x tile once (fp32 -> bf16); contiguous 12288 floats
#pragma unroll
  for (int i = 0; i < 12; ++i) {
    int idx = threadIdx.x + 256 * i;
    float4 f = ((const float4*)xrow)[idx];
    int r = idx / 48, k4 = (idx % 48) * 4;
    ushort4 a;
    a.x = f2b(f.x); a.y = f2b(f.y); a.z = f2b(f.z); a.w = f2b(f.w);
    *(ushort4*)&xs[r][k4] = a;
  }
  const int lane = threadIdx.x & 63;
  const int wv = threadIdx.x >> 6;
  const int wm = wv >> 1, wn = wv & 1;
  const int lr = lane & 15, g = lane >> 4;
  const f32x4_t zro = {0.f, 0.f, 0.f, 0.f};
  for (int cseg = 0; cseg < 9; ++cseg) {
    __syncthreads();
    const u16* wrow = w_bf + (size_t)cseg * 64 * 192;
#pragma unroll
    for (int i = 0; i < 6; ++i) {
      int idx = threadIdx.x + 256 * i;  // 16B chunks
      float4 f = ((const float4*)wrow)[idx];
      *(float4*)&wsx[idx / 24][(idx % 24) * 8] = f;
    }
    __syncthreads();
    f32x4_t acc[2][2];
    acc[0][0] = zro; acc[0][1] = zro; acc[1][0] = zro; acc[1][1] = zro;
#pragma unroll
    for (int ks = 0; ks < 6; ++ks) {
      bf16x8_t af[2], bfr[2];
#pragma unroll
      for (int t2 = 0; t2 < 2; ++t2) {
        af[t2] = *(const bf16x8_t*)&xs[wm * 32 + t2 * 16 + lr][ks * 32 + g * 8];
        bfr[t2] = *(const bf16x8_t*)&wsx[wn * 32 + t2 * 16 + lr][ks * 32 + g * 8];
      }
#pragma unroll
      for (int mt = 0; mt < 2; ++mt)
#pragma unroll
        for (int nt = 0; nt < 2; ++nt)
          acc[mt][nt] = __builtin_amdgcn_mfma_f32_16x16x32_bf16(af[mt], bfr[nt], acc[mt][nt], 0, 0, 0);
    }
    const int c0 = cseg * 64;
    const int seg = c0 / 192;  // 0=q 1=k 2=v, uniform per cseg
    u16* dst = (seg == 0) ? qb : ((seg == 1) ? kb : vb);
    const float scl = (seg == 0) ? 0.17677669529663687f : 1.0f;
#pragma unroll
    for (int mt = 0; mt < 2; ++mt) {
#pragma unroll
      for (int nt = 0; nt < 2; ++nt) {
        int gc = c0 + wn * 32 + nt * 16 + lr;
        float bias = qkv_b[gc];
        int c2 = gc - seg * 192;
        int h = c2 >> 5, d = c2 & 31;
#pragma unroll
        for (int r = 0; r < 4; ++r) {
          int gr = m0 + wm * 32 + mt * 16 + g * 4 + r;
          int b_ = gr / 343;
          int n = gr - b_ * 343;
          dst[(((size_t)b_ * 6 + h) * 343 + n) * 32 + d] = f2b((acc[mt][nt][r] + bias) * scl);
        }
      }
    }
  }
}

// ---------------- fused attention per (row-tile, b*h) ----------------
// 8 waves x 16 q-rows. Swapped QK^T: S^T = K·Q^T so each lane owns one q-row.
__global__ __launch_bounds__(512) void attn_k(const u16* __restrict__ qg,
                                              const u16* __restrict__ kg,
                                              const u16* __restrict__ vg,
                                              const u16* __restrict__ bias_bf,
                                              const u16* __restrict__ mask_bf,
                                              u16* __restrict__ ao) {
  __shared__ u16 ksm[352][40];  // K [kc][d], +8 pad; rows >=343 garbage (masked later)
  __shared__ u16 vtm[32][360];  // V^T [d][kc], cols >=343 zeroed
  const int tile = blockIdx.x;  // 0..2
  const int bh = blockIdx.y;    // 0..1535
  const int b_ = bh / 6;
  const int h = bh - b_ * 6;
  const int w = b_ & 63;
  const int t = threadIdx.x;
  const u16* kbh = kg + (size_t)bh * 10976;
  const u16* vbh = vg + (size_t)bh * 10976;
  for (int i = t; i < 1372; i += 512) {  // K: 16B chunks
    float4 f = ((const float4*)kbh)[i];
    *(float4*)&ksm[i >> 2][(i & 3) * 8] = f;
  }
  for (int i = t; i < 10976; i += 512) {  // V transpose
    vtm[i & 31][i >> 5] = vbh[i];
  }
  for (int i = t; i < 288; i += 512) {  // zero V^T pad cols (NaN safety in MFMA)
    vtm[i / 9][343 + (i % 9)] = 0;
  }
  __syncthreads();
  const int lane = t & 63;
  const int wv = t >> 6;
  const int q0 = tile * 128 + wv * 16;
  if (q0 >= 343) return;  // no barriers after this point
  const int lr = lane & 15, g = lane >> 4;
  const int qi = q0 + lr;
  const bool qv = qi < 343;
  const int qic = qv ? qi : 342;
  FragU qfu;
  qfu.u[0] = 0u; qfu.u[1] = 0u; qfu.u[2] = 0u; qfu.u[3] = 0u;
  if (qv) qfu.v = *(const bf16x8_t*)(qg + ((size_t)bh * 343 + qi) * 32 + g * 8);
  const f32x4_t zro = {0.f, 0.f, 0.f, 0.f};
  // S^T tiles: st[ct][r] = S[q0+lr][kc = ct*16 + 4*g + r] (times scale, folded into q)
  f32x4_t st[22];
#pragma unroll
  for (int ct = 0; ct < 22; ++ct) {
    bf16x8_t af = *(const bf16x8_t*)&ksm[ct * 16 + lr][g * 8];
    st[ct] = __builtin_amdgcn_mfma_f32_16x16x32_bf16(af, qfu.v, zro, 0, 0, 0);
  }
  const u16* brow = bias_bf + ((size_t)h * 343 + qic) * 352;
  const u16* mrow = mask_bf + ((size_t)w * 343 + qic) * 352;
  float mx = -3e38f;
#pragma unroll
  for (int ct = 0; ct < 22; ++ct) {
    int kjb = ct * 16 + 4 * g;
    union { ushort4 v; u16 s[4]; } bv, mv;
    bv.v = *(const ushort4*)&brow[kjb];
    mv.v = *(const ushort4*)&mrow[kjb];
#pragma unroll
    for (int r = 0; r < 4; ++r) {
      float s = (kjb + r < 343) ? (st[ct][r] + b2f(bv.s[r]) + b2f(mv.s[r])) : -1e30f;
      st[ct][r] = s;
      mx = fmaxf(mx, s);
    }
  }
  // row reduce across the 4 replicas of each q-row
  mx = fmaxf(mx, __shfl_xor(mx, 16, 64));
  mx = fmaxf(mx, __shfl_xor(mx, 32, 64));
  float sum = 0.f;
  unsigned int pk[22][2];  // bf16-packed unnormalized P
#pragma unroll
  for (int ct = 0; ct < 22; ++ct) {
    float e0 = __expf(st[ct][0] - mx);
    float e1 = __expf(st[ct][1] - mx);
    float e2 = __expf(st[ct][2] - mx);
    float e3 = __expf(st[ct][3] - mx);
    sum += (e0 + e1) + (e2 + e3);
    pk[ct][0] = (unsigned int)f2b(e0) | ((unsigned int)f2b(e1) << 16);
    pk[ct][1] = (unsigned int)f2b(e2) | ((unsigned int)f2b(e3) << 16);
  }
  sum += __shfl_xor(sum, 16, 64);
  sum += __shfl_xor(sum, 32, 64);
  const float inv = 1.0f / sum;
  // O^T = V^T · P^T ; B-frag (P^T) gathered from pk via shuffles
  f32x4_t oa[2] = {zro, zro};
  const int base = lr + ((g & 1) << 5);
  const bool selhi = (g >> 1) != 0;
#pragma unroll
  for (int ks = 0; ks < 11; ++ks) {
    unsigned int a0 = shflu(pk[2 * ks][0], base);
    unsigned int a1 = shflu(pk[2 * ks][1], base);
    unsigned int a2 = shflu(pk[2 * ks][0], base + 16);
    unsigned int a3 = shflu(pk[2 * ks][1], base + 16);
    unsigned int c0 = shflu(pk[2 * ks + 1][0], base);
    unsigned int c1 = shflu(pk[2 * ks + 1][1], base);
    unsigned int c2 = shflu(pk[2 * ks + 1][0], base + 16);
    unsigned int c3 = shflu(pk[2 * ks + 1][1], base + 16);
    FragU bu;
    bu.u[0] = selhi ? c0 : a0;
    bu.u[1] = selhi ? c1 : a1;
    bu.u[2] = selhi ? c2 : a2;
    bu.u[3] = selhi ? c3 : a3;
#pragma unroll
    for (int mt = 0; mt < 2; ++mt) {
      bf16x8_t vf = *(const bf16x8_t*)&vtm[mt * 16 + lr][ks * 32 + g * 8];
      oa[mt] = __builtin_amdgcn_mfma_f32_16x16x32_bf16(vf, bu.v, oa[mt], 0, 0, 0);
    }
  }
  if (qv) {
    u16* orow = ao + ((size_t)b_ * 343 + qi) * 192 + h * 32;
#pragma unroll
    for (int mt = 0; mt < 2; ++mt) {
      ushort4 sv;
      sv.x = f2b(oa[mt][0] * inv);
      sv.y = f2b(oa[mt][1] * inv);
      sv.z = f2b(oa[mt][2] * inv);
      sv.w = f2b(oa[mt][3] * inv);
      *(ushort4*)&orow[mt * 16 + 4 * g] = sv;
    }
  }
}

// ---------------- proj GEMM: [87808,192] bf16 x [192,192]^T + b -> fp32 out ----------------
__global__ __launch_bounds__(256) void proj_gemm(const u16* __restrict__ ao,
                                                 const u16* __restrict__ wp_bf,
                                                 const float* __restrict__ proj_b,
                                                 float* __restrict__ out) {
  __shared__ u16 as_[64][200];
  __shared__ u16 wsx[64][200];
  const int m0 = blockIdx.x * 64;
  const u16* arow = ao + (size_t)m0 * 192;
#pragma unroll
  for (int i = 0; i < 6; ++i) {
    int idx = threadIdx.x + 256 * i;
    float4 f = ((const float4*)arow)[idx];
    *(float4*)&as_[idx / 24][(idx % 24) * 8] = f;
  }
  const int lane = threadIdx.x & 63;
  const int wv = threadIdx.x >> 6;
  const int wm = wv >> 1, wn = wv & 1;
  const int lr = lane & 15, g = lane >> 4;
  const f32x4_t zro = {0.f, 0.f, 0.f, 0.f};
  for (int cseg = 0; cseg < 3; ++cseg) {
    __syncthreads();
    const u16* wrow = wp_bf + (size_t)cseg * 64 * 192;
#pragma unroll
    for (int i = 0; i < 6; ++i) {
      int idx = threadIdx.x + 256 * i;
      float4 f = ((const float4*)wrow)[idx];
      *(float4*)&wsx[idx / 24][(idx % 24) * 8] = f;
    }
    __syncthreads();
    f32x4_t acc[2][2];
    acc[0][0] = zro; acc[0][1] = zro; acc[1][0] = zro; acc[1][1] = zro;
#pragma unroll
    for (int ks = 0; ks < 6; ++ks) {
      bf16x8_t af[2], bfr[2];
#pragma unroll
      for (int t2 = 0; t2 < 2; ++t2) {
        af[t2] = *(const bf16x8_t*)&as_[wm * 32 + t2 * 16 + lr][ks * 32 + g * 8];
        bfr[t2] = *(const bf16x8_t*)&wsx[wn * 32 + t2 * 16 + lr][ks * 32 + g * 8];
      }
#pragma unroll
      for (int mt = 0; mt < 2; ++mt)
#pragma unroll
        for (int nt = 0; nt < 2; ++nt)
          acc[mt][nt] = __builtin_amdgcn_mfma_f32_16x16x32_bf16(af[mt], bfr[nt], acc[mt][nt], 0, 0, 0);
    }
    const int c0 = cseg * 64;
#pragma unroll
    for (int mt = 0; mt < 2; ++mt) {
#pragma unroll
      for (int nt = 0; nt < 2; ++nt) {
        int gc = c0 + wn * 32 + nt * 16 + lr;
        float bias = proj_b[gc];
#pragma unroll
        for (int r = 0; r < 4; ++r) {
          int gr = m0 + wm * 32 + mt * 16 + g * 4 + r;
          out[(size_t)gr * 192 + gc] = acc[mt][nt][r] + bias;
        }
      }
    }
  }
}

extern "C" void kernel_launch(void* const* d_in, const int* in_sizes, int n_in,
                              void* d_out, int out_size, void* d_ws, size_t ws_size,
                              hipStream_t stream) {
  const float* x = (const float*)d_in[0];
  const float* mask = (const float*)d_in[1];
  const float* qkv_w = (const float*)d_in[2];
  const float* qkv_b = (const float*)d_in[3];
  const float* proj_w = (const float*)d_in[4];
  const float* proj_b = (const float*)d_in[5];
  const float* bias_table = (const float*)d_in[6];
  const int* rel_index = (const int*)d_in[7];
  float* out = (float*)d_out;
  char* ws = (char*)d_ws;

  // ws layout (bytes)
  u16* qb      = (u16*)(ws + 0);          // 33,718,272
  u16* kb      = (u16*)(ws + 33718272);   // 33,718,272
  u16* vb      = (u16*)(ws + 67436544);   // 33,718,272
  u16* ao      = (u16*)(ws + 101154816);  // 33,718,272
  u16* bias_bf = (u16*)(ws + 134873088);  // 1,449,216
  u16* mask_bf = (u16*)(ws + 136322304);  // 15,458,304
  u16* wq_bf   = (u16*)(ws + 151780608);  // 221,184
  u16* wp_bf   = (u16*)(ws + 152001792);  // 73,728 -> end 152,075,520

  prep_bias_k<<<2758, 256, 0, stream>>>(bias_table, rel_index, bias_bf);
  prep_mask_k<<<29413, 256, 0, stream>>>(mask, mask_bf);
  prep_w_k<<<576, 256, 0, stream>>>(qkv_w, proj_w, wq_bf, wp_bf);
  qkv_gemm<<<1372, 256, 0, stream>>>(x, wq_bf, qkv_b, qb, kb, vb);
  attn_k<<<dim3(3, 1536), 512, 0, stream>>>(qb, kb, vb, bias_bf, mask_bf, ao);
  proj_gemm<<<1372, 256, 0, stream>>>(ao, wp_bf, proj_b, out);
}

// Round 2
// 281.115 us; speedup vs baseline: 1.1397x; 1.1397x over previous
//
#include <hip/hip_runtime.h>

typedef __bf16 bf16x8_t __attribute__((ext_vector_type(8)));
typedef float f32x4_t __attribute__((ext_vector_type(4)));
typedef unsigned short u16;
typedef unsigned long long u64;

__device__ __forceinline__ u16 f2b(float f) {
  __bf16 h = (__bf16)f;
  u16 u;
  __builtin_memcpy(&u, &h, 2);
  return u;
}
__device__ __forceinline__ float b2f(u16 u) {
  unsigned int i = ((unsigned int)u) << 16;
  float f;
  __builtin_memcpy(&f, &i, 4);
  return f;
}
__device__ __forceinline__ unsigned int shflu(unsigned int v, int s) {
  return (unsigned int)__shfl((int)v, s, 64);
}

union FragU { unsigned int u[4]; bf16x8_t v; };

// ---------------- prep: bias gather -> bf16 [6][343][352], pad cols zeroed ----------------
__global__ void prep_bias_k(const float* __restrict__ bias_table,
                            const int* __restrict__ rel_index,
                            u16* __restrict__ bias_bf) {
  int i = blockIdx.x * 256 + threadIdx.x;
  if (i >= 6 * 343 * 352) return;
  int h = i / (343 * 352);
  int rem = i - h * (343 * 352);
  int r = rem / 352;
  int c = rem - r * 352;
  u16 val = 0;
  if (c < 343) {
    int idx = rel_index[r * 343 + c];
    val = f2b(bias_table[idx * 6 + h]);
  }
  bias_bf[((size_t)h * 343 + r) * 352 + c] = val;
}

// ---------------- prep: mask -> bit table [64*343][6] u64 (bit=1 means masked) ----------------
__global__ void prep_maskbits_k(const float* __restrict__ mask, u64* __restrict__ mbits) {
  int row = blockIdx.x * 4 + (threadIdx.x >> 6);  // 0..21951
  int lane = threadIdx.x & 63;
  const float* mrow = mask + (size_t)row * 343;
#pragma unroll
  for (int it = 0; it < 6; ++it) {
    int idx = it * 64 + lane;
    float v = (idx < 343) ? mrow[idx] : -100.0f;  // pad cols masked
    u64 b = __ballot(v < -50.0f);
    if (lane == 0) mbits[(size_t)row * 6 + it] = b;
  }
}

// ---------------- prep: weights fp32 -> bf16 ----------------
__global__ void prep_w_k(const float* __restrict__ qkv_w, const float* __restrict__ proj_w,
                         u16* __restrict__ wq, u16* __restrict__ wp) {
  int i = blockIdx.x * 256 + threadIdx.x;
  if (i < 110592) wq[i] = f2b(qkv_w[i]);
  int j = i - 110592;
  if (j >= 0 && j < 36864) wp[j] = f2b(proj_w[j]);
}

// ---------------- QKV GEMM: [87808,192] x [576,192]^T -> q,k,v bf16 [b,h,n,32] ----------------
__global__ __launch_bounds__(256) void qkv_gemm(const float* __restrict__ x,
                                                const u16* __restrict__ w_bf,
                                                const float* __restrict__ qkv_b,
                                                u16* __restrict__ qb,
                                                u16* __restrict__ kb,
                                                u16* __restrict__ vb) {
  __shared__ u16 xs[64][200];   // +8 pad
  __shared__ u16 wsx[64][200];
  const int m0 = blockIdx.x * 64;
  const float* xrow = x + (size_t)m0 * 192;
#pragma unroll
  for (int i = 0; i < 12; ++i) {
    int idx = threadIdx.x + 256 * i;
    float4 f = ((const float4*)xrow)[idx];
    int r = idx / 48, k4 = (idx % 48) * 4;
    ushort4 a;
    a.x = f2b(f.x); a.y = f2b(f.y); a.z = f2b(f.z); a.w = f2b(f.w);
    *(ushort4*)&xs[r][k4] = a;
  }
  const int lane = threadIdx.x & 63;
  const int wv = threadIdx.x >> 6;
  const int wm = wv >> 1, wn = wv & 1;
  const int lr = lane & 15, g = lane >> 4;
  const f32x4_t zro = {0.f, 0.f, 0.f, 0.f};
  for (int cseg = 0; cseg < 9; ++cseg) {
    __syncthreads();
    const u16* wrow = w_bf + (size_t)cseg * 64 * 192;
#pragma unroll
    for (int i = 0; i < 6; ++i) {
      int idx = threadIdx.x + 256 * i;  // 16B chunks
      float4 f = ((const float4*)wrow)[idx];
      *(float4*)&wsx[idx / 24][(idx % 24) * 8] = f;
    }
    __syncthreads();
    f32x4_t acc[2][2];
    acc[0][0] = zro; acc[0][1] = zro; acc[1][0] = zro; acc[1][1] = zro;
#pragma unroll
    for (int ks = 0; ks < 6; ++ks) {
      bf16x8_t af[2], bfr[2];
#pragma unroll
      for (int t2 = 0; t2 < 2; ++t2) {
        af[t2] = *(const bf16x8_t*)&xs[wm * 32 + t2 * 16 + lr][ks * 32 + g * 8];
        bfr[t2] = *(const bf16x8_t*)&wsx[wn * 32 + t2 * 16 + lr][ks * 32 + g * 8];
      }
#pragma unroll
      for (int mt = 0; mt < 2; ++mt)
#pragma unroll
        for (int nt = 0; nt < 2; ++nt)
          acc[mt][nt] = __builtin_amdgcn_mfma_f32_16x16x32_bf16(af[mt], bfr[nt], acc[mt][nt], 0, 0, 0);
    }
    const int c0 = cseg * 64;
    const int seg = c0 / 192;  // 0=q 1=k 2=v
    u16* dst = (seg == 0) ? qb : ((seg == 1) ? kb : vb);
    const float scl = (seg == 0) ? 0.17677669529663687f : 1.0f;
#pragma unroll
    for (int mt = 0; mt < 2; ++mt) {
#pragma unroll
      for (int nt = 0; nt < 2; ++nt) {
        int gc = c0 + wn * 32 + nt * 16 + lr;
        float bias = qkv_b[gc];
        int c2 = gc - seg * 192;
        int h = c2 >> 5, d = c2 & 31;
#pragma unroll
        for (int r = 0; r < 4; ++r) {
          int gr = m0 + wm * 32 + mt * 16 + g * 4 + r;
          int b_ = gr / 343;
          int n = gr - b_ * 343;
          dst[(((size_t)b_ * 6 + h) * 343 + n) * 32 + d] = f2b((acc[mt][nt][r] + bias) * scl);
        }
      }
    }
  }
}

// ---------------- fused attention: one block per (b,h), 8 waves x 3 row-tile passes ----------------
__global__ __launch_bounds__(512, 4) void attn_k(const u16* __restrict__ qg,
                                                 const u16* __restrict__ kg,
                                                 const u16* __restrict__ vg,
                                                 const u16* __restrict__ bias_bf,
                                                 const u64* __restrict__ mbits,
                                                 u16* __restrict__ ao) {
  __shared__ u16 ksm[352][40];  // K [kc][d], +8 pad; rows 343..351 zeroed
  __shared__ u16 vtm[32][360];  // V^T [d][kc], cols 343..359 zeroed
  const int bh = blockIdx.x;    // 0..1535
  const int b_ = bh / 6;
  const int h = bh - b_ * 6;
  const int w = b_ & 63;
  const int t = threadIdx.x;
  const int lane = t & 63;
  const int wv = t >> 6;
  const u16* kbh = kg + (size_t)bh * 10976;
  const u16* vbh = vg + (size_t)bh * 10976;
  // stage K (343 rows x 32 d), 4 float4 per row
  for (int i = t; i < 1372; i += 512) {
    float4 f = ((const float4*)kbh)[i];
    *(float4*)&ksm[i >> 2][(i & 3) * 8] = f;
  }
  if (t < 360) ksm[343 + t / 40][t % 40] = 0;  // zero K pad rows
  // stage V transposed: each lane owns a distinct column n -> write bank ~2-way
#pragma unroll
  for (int k = 0; k < 3; ++k) {
    int dq = t >> 7;                   // 0..3, uniform per wave-pair
    int n = k * 128 + (t & 127);
    if (n < 343) {
      union { float4 f4; u16 s[8]; } u;
      u.f4 = ((const float4*)vbh)[n * 4 + dq];
#pragma unroll
      for (int j = 0; j < 8; ++j) vtm[dq * 8 + j][n] = u.s[j];
    }
  }
  for (int i = t; i < 544; i += 512) vtm[i / 17][343 + i % 17] = 0;  // zero V pad cols
  __syncthreads();
  const int lr = lane & 15, g = lane >> 4;
  const f32x4_t zro = {0.f, 0.f, 0.f, 0.f};
  for (int pass = 0; pass < 3; ++pass) {
    const int rt = pass * 8 + wv;  // row-tile 0..21
    if (rt >= 22) break;
    const int q0 = rt * 16;
    const int qi = q0 + lr;
    const bool qv = qi < 343;
    const int qic = qv ? qi : 342;
    FragU qfu;
    qfu.u[0] = 0u; qfu.u[1] = 0u; qfu.u[2] = 0u; qfu.u[3] = 0u;
    if (qv) qfu.v = *(const bf16x8_t*)(qg + ((size_t)bh * 343 + qi) * 32 + g * 8);
    // S^T: st[ct][r] = S[qi][kc = ct*16 + 4*g + r]  (scale folded into q)
    f32x4_t st[22];
#pragma unroll
    for (int ct = 0; ct < 22; ++ct) {
      bf16x8_t af = *(const bf16x8_t*)&ksm[ct * 16 + lr][g * 8];
      st[ct] = __builtin_amdgcn_mfma_f32_16x16x32_bf16(af, qfu.v, zro, 0, 0, 0);
    }
    const u16* brow = bias_bf + ((size_t)h * 343 + qic) * 352;
    const u64* mrow = mbits + ((size_t)w * 343 + qic) * 6;
    u64 mw[6];
#pragma unroll
    for (int i2 = 0; i2 < 6; ++i2) mw[i2] = mrow[i2];
    float mx = 0.0f;  // max(mx,0) guard: keeps pad exp <= e^-100, softmax invariant
#pragma unroll
    for (int ct = 0; ct < 22; ++ct) {
      int kjb = ct * 16 + 4 * g;
      union { ushort4 v; u16 s[4]; } bv;
      bv.v = *(const ushort4*)&brow[kjb];
      unsigned int bits4 = (unsigned int)(mw[ct >> 2] >> ((ct & 3) * 16 + 4 * g)) & 0xFu;
#pragma unroll
      for (int r = 0; r < 4; ++r) {
        float s = st[ct][r] + b2f(bv.s[r]) + (((bits4 >> r) & 1u) ? -100.0f : 0.0f);
        st[ct][r] = s;
        mx = fmaxf(mx, s);
      }
    }
    mx = fmaxf(mx, __shfl_xor(mx, 16, 64));
    mx = fmaxf(mx, __shfl_xor(mx, 32, 64));
    float sum = 0.f;
    unsigned int pk[22][2];  // bf16-packed unnormalized P
#pragma unroll
    for (int ct = 0; ct < 22; ++ct) {
      float e0 = __expf(st[ct][0] - mx);
      float e1 = __expf(st[ct][1] - mx);
      float e2 = __expf(st[ct][2] - mx);
      float e3 = __expf(st[ct][3] - mx);
      sum += (e0 + e1) + (e2 + e3);
      pk[ct][0] = (unsigned int)f2b(e0) | ((unsigned int)f2b(e1) << 16);
      pk[ct][1] = (unsigned int)f2b(e2) | ((unsigned int)f2b(e3) << 16);
    }
    sum += __shfl_xor(sum, 16, 64);
    sum += __shfl_xor(sum, 32, 64);
    const float inv = 1.0f / sum;
    // O^T = V^T · P^T ; B-frag (P^T) gathered from pk via shuffles
    f32x4_t oa[2] = {zro, zro};
    const int base = lr + ((g & 1) << 5);
    const bool selhi = (g >> 1) != 0;
#pragma unroll
    for (int ks = 0; ks < 11; ++ks) {
      unsigned int a0 = shflu(pk[2 * ks][0], base);
      unsigned int a1 = shflu(pk[2 * ks][1], base);
      unsigned int a2 = shflu(pk[2 * ks][0], base + 16);
      unsigned int a3 = shflu(pk[2 * ks][1], base + 16);
      unsigned int c0 = shflu(pk[2 * ks + 1][0], base);
      unsigned int c1 = shflu(pk[2 * ks + 1][1], base);
      unsigned int c2 = shflu(pk[2 * ks + 1][0], base + 16);
      unsigned int c3 = shflu(pk[2 * ks + 1][1], base + 16);
      FragU bu;
      bu.u[0] = selhi ? c0 : a0;
      bu.u[1] = selhi ? c1 : a1;
      bu.u[2] = selhi ? c2 : a2;
      bu.u[3] = selhi ? c3 : a3;
#pragma unroll
      for (int mt = 0; mt < 2; ++mt) {
        bf16x8_t vf = *(const bf16x8_t*)&vtm[mt * 16 + lr][ks * 32 + g * 8];
        oa[mt] = __builtin_amdgcn_mfma_f32_16x16x32_bf16(vf, bu.v, oa[mt], 0, 0, 0);
      }
    }
    if (qv) {
      u16* orow = ao + ((size_t)b_ * 343 + qi) * 192 + h * 32;
#pragma unroll
      for (int mt = 0; mt < 2; ++mt) {
        ushort4 sv;
        sv.x = f2b(oa[mt][0] * inv);
        sv.y = f2b(oa[mt][1] * inv);
        sv.z = f2b(oa[mt][2] * inv);
        sv.w = f2b(oa[mt][3] * inv);
        *(ushort4*)&orow[mt * 16 + 4 * g] = sv;
      }
    }
  }
}

// ---------------- proj GEMM: [87808,192] bf16 x [192,192]^T + b -> fp32 out ----------------
__global__ __launch_bounds__(256) void proj_gemm(const u16* __restrict__ ao,
                                                 const u16* __restrict__ wp_bf,
                                                 const float* __restrict__ proj_b,
                                                 float* __restrict__ out) {
  __shared__ u16 as_[64][200];
  __shared__ u16 wsx[64][200];
  const int m0 = blockIdx.x * 64;
  const u16* arow = ao + (size_t)m0 * 192;
#pragma unroll
  for (int i = 0; i < 6; ++i) {
    int idx = threadIdx.x + 256 * i;
    float4 f = ((const float4*)arow)[idx];
    *(float4*)&as_[idx / 24][(idx % 24) * 8] = f;
  }
  const int lane = threadIdx.x & 63;
  const int wv = threadIdx.x >> 6;
  const int wm = wv >> 1, wn = wv & 1;
  const int lr = lane & 15, g = lane >> 4;
  const f32x4_t zro = {0.f, 0.f, 0.f, 0.f};
  for (int cseg = 0; cseg < 3; ++cseg) {
    __syncthreads();
    const u16* wrow = wp_bf + (size_t)cseg * 64 * 192;
#pragma unroll
    for (int i = 0; i < 6; ++i) {
      int idx = threadIdx.x + 256 * i;
      float4 f = ((const float4*)wrow)[idx];
      *(float4*)&wsx[idx / 24][(idx % 24) * 8] = f;
    }
    __syncthreads();
    f32x4_t acc[2][2];
    acc[0][0] = zro; acc[0][1] = zro; acc[1][0] = zro; acc[1][1] = zro;
#pragma unroll
    for (int ks = 0; ks < 6; ++ks) {
      bf16x8_t af[2], bfr[2];
#pragma unroll
      for (int t2 = 0; t2 < 2; ++t2) {
        af[t2] = *(const bf16x8_t*)&as_[wm * 32 + t2 * 16 + lr][ks * 32 + g * 8];
        bfr[t2] = *(const bf16x8_t*)&wsx[wn * 32 + t2 * 16 + lr][ks * 32 + g * 8];
      }
#pragma unroll
      for (int mt = 0; mt < 2; ++mt)
#pragma unroll
        for (int nt = 0; nt < 2; ++nt)
          acc[mt][nt] = __builtin_amdgcn_mfma_f32_16x16x32_bf16(af[mt], bfr[nt], acc[mt][nt], 0, 0, 0);
    }
    const int c0 = cseg * 64;
#pragma unroll
    for (int mt = 0; mt < 2; ++mt) {
#pragma unroll
      for (int nt = 0; nt < 2; ++nt) {
        int gc = c0 + wn * 32 + nt * 16 + lr;
        float bias = proj_b[gc];
#pragma unroll
        for (int r = 0; r < 4; ++r) {
          int gr = m0 + wm * 32 + mt * 16 + g * 4 + r;
          out[(size_t)gr * 192 + gc] = acc[mt][nt][r] + bias;
        }
      }
    }
  }
}

extern "C" void kernel_launch(void* const* d_in, const int* in_sizes, int n_in,
                              void* d_out, int out_size, void* d_ws, size_t ws_size,
                              hipStream_t stream) {
  const float* x = (const float*)d_in[0];
  const float* mask = (const float*)d_in[1];
  const float* qkv_w = (const float*)d_in[2];
  const float* qkv_b = (const float*)d_in[3];
  const float* proj_w = (const float*)d_in[4];
  const float* proj_b = (const float*)d_in[5];
  const float* bias_table = (const float*)d_in[6];
  const int* rel_index = (const int*)d_in[7];
  float* out = (float*)d_out;
  char* ws = (char*)d_ws;

  // ws layout (bytes)
  u16* qb      = (u16*)(ws + 0);          // 33,718,272
  u16* kb      = (u16*)(ws + 33718272);   // 33,718,272
  u16* vb      = (u16*)(ws + 67436544);   // 33,718,272
  u16* ao      = (u16*)(ws + 101154816);  // 33,718,272
  u16* bias_bf = (u16*)(ws + 134873088);  // 1,449,216
  u64* mbits   = (u64*)(ws + 136322304);  // 1,053,696
  u16* wq_bf   = (u16*)(ws + 137376000);  // 221,184
  u16* wp_bf   = (u16*)(ws + 137597184);  // 73,728 -> end 137,670,912

  prep_bias_k<<<2830, 256, 0, stream>>>(bias_table, rel_index, bias_bf);
  prep_maskbits_k<<<5488, 256, 0, stream>>>(mask, mbits);
  prep_w_k<<<576, 256, 0, stream>>>(qkv_w, proj_w, wq_bf, wp_bf);
  qkv_gemm<<<1372, 256, 0, stream>>>(x, wq_bf, qkv_b, qb, kb, vb);
  attn_k<<<1536, 512, 0, stream>>>(qb, kb, vb, bias_bf, mbits, ao);
  proj_gemm<<<1372, 256, 0, stream>>>(ao, wp_bf, proj_b, out);
}

// Round 3
// 227.964 us; speedup vs baseline: 1.4054x; 1.2332x over previous
//
#include <hip/hip_runtime.h>

typedef __bf16 bf16x8_t __attribute__((ext_vector_type(8)));
typedef float f32x4_t __attribute__((ext_vector_type(4)));
typedef unsigned short u16;
typedef unsigned long long u64;

__device__ __forceinline__ u16 f2b(float f) {
  __bf16 h = (__bf16)f;
  u16 u;
  __builtin_memcpy(&u, &h, 2);
  return u;
}
__device__ __forceinline__ float b2f(u16 u) {
  unsigned int i = ((unsigned int)u) << 16;
  float f;
  __builtin_memcpy(&f, &i, 4);
  return f;
}
__device__ __forceinline__ unsigned int shflu(unsigned int v, int s) {
  return (unsigned int)__shfl((int)v, s, 64);
}

union FragU { unsigned int u[4]; bf16x8_t v; };

// ---------------- prep: bias gather -> bf16 [6][343][352], pad cols zeroed ----------------
__global__ void prep_bias_k(const float* __restrict__ bias_table,
                            const int* __restrict__ rel_index,
                            u16* __restrict__ bias_bf) {
  int i = blockIdx.x * 256 + threadIdx.x;
  if (i >= 6 * 343 * 352) return;
  int h = i / (343 * 352);
  int rem = i - h * (343 * 352);
  int r = rem / 352;
  int c = rem - r * 352;
  u16 val = 0;
  if (c < 343) {
    int idx = rel_index[r * 343 + c];
    val = f2b(bias_table[idx * 6 + h]);
  }
  bias_bf[((size_t)h * 343 + r) * 352 + c] = val;
}

// ---------------- prep: mask -> bit table [64*343][6] u64 (bit=1 means masked) ----------------
__global__ void prep_maskbits_k(const float* __restrict__ mask, u64* __restrict__ mbits) {
  int row = blockIdx.x * 4 + (threadIdx.x >> 6);  // 0..21951
  int lane = threadIdx.x & 63;
  const float* mrow = mask + (size_t)row * 343;
#pragma unroll
  for (int it = 0; it < 6; ++it) {
    int idx = it * 64 + lane;
    float v = (idx < 343) ? mrow[idx] : -100.0f;  // pad cols masked
    u64 b = __ballot(v < -50.0f);
    if (lane == 0) mbits[(size_t)row * 6 + it] = b;
  }
}

// ---------------- prep: weights fp32 -> bf16 ----------------
__global__ void prep_w_k(const float* __restrict__ qkv_w, const float* __restrict__ proj_w,
                         u16* __restrict__ wq, u16* __restrict__ wp) {
  int i = blockIdx.x * 256 + threadIdx.x;
  if (i < 110592) wq[i] = f2b(qkv_w[i]);
  int j = i - 110592;
  if (j >= 0 && j < 36864) wp[j] = f2b(proj_w[j]);
}

// ---------------- QKV GEMM: [87808,192] x [576,192]^T -> q,k,v bf16 [b,h,n,32] ----------------
__global__ __launch_bounds__(256) void qkv_gemm(const float* __restrict__ x,
                                                const u16* __restrict__ w_bf,
                                                const float* __restrict__ qkv_b,
                                                u16* __restrict__ qb,
                                                u16* __restrict__ kb,
                                                u16* __restrict__ vb) {
  __shared__ u16 xs[64][200];   // +8 pad
  __shared__ u16 wsx[64][200];
  const int m0 = blockIdx.x * 64;
  const float* xrow = x + (size_t)m0 * 192;
#pragma unroll
  for (int i = 0; i < 12; ++i) {
    int idx = threadIdx.x + 256 * i;
    float4 f = ((const float4*)xrow)[idx];
    int r = idx / 48, k4 = (idx % 48) * 4;
    ushort4 a;
    a.x = f2b(f.x); a.y = f2b(f.y); a.z = f2b(f.z); a.w = f2b(f.w);
    *(ushort4*)&xs[r][k4] = a;
  }
  const int lane = threadIdx.x & 63;
  const int wv = threadIdx.x >> 6;
  const int wm = wv >> 1, wn = wv & 1;
  const int lr = lane & 15, g = lane >> 4;
  const f32x4_t zro = {0.f, 0.f, 0.f, 0.f};
  for (int cseg = 0; cseg < 9; ++cseg) {
    __syncthreads();
    const u16* wrow = w_bf + (size_t)cseg * 64 * 192;
#pragma unroll
    for (int i = 0; i < 6; ++i) {
      int idx = threadIdx.x + 256 * i;  // 16B chunks
      float4 f = ((const float4*)wrow)[idx];
      *(float4*)&wsx[idx / 24][(idx % 24) * 8] = f;
    }
    __syncthreads();
    f32x4_t acc[2][2];
    acc[0][0] = zro; acc[0][1] = zro; acc[1][0] = zro; acc[1][1] = zro;
#pragma unroll
    for (int ks = 0; ks < 6; ++ks) {
      bf16x8_t af[2], bfr[2];
#pragma unroll
      for (int t2 = 0; t2 < 2; ++t2) {
        af[t2] = *(const bf16x8_t*)&xs[wm * 32 + t2 * 16 + lr][ks * 32 + g * 8];
        bfr[t2] = *(const bf16x8_t*)&wsx[wn * 32 + t2 * 16 + lr][ks * 32 + g * 8];
      }
#pragma unroll
      for (int mt = 0; mt < 2; ++mt)
#pragma unroll
        for (int nt = 0; nt < 2; ++nt)
          acc[mt][nt] = __builtin_amdgcn_mfma_f32_16x16x32_bf16(af[mt], bfr[nt], acc[mt][nt], 0, 0, 0);
    }
    const int c0 = cseg * 64;
    const int seg = c0 / 192;  // 0=q 1=k 2=v
    u16* dst = (seg == 0) ? qb : ((seg == 1) ? kb : vb);
    const float scl = (seg == 0) ? 0.17677669529663687f : 1.0f;
#pragma unroll
    for (int mt = 0; mt < 2; ++mt) {
#pragma unroll
      for (int nt = 0; nt < 2; ++nt) {
        int gc = c0 + wn * 32 + nt * 16 + lr;
        float bias = qkv_b[gc];
        int c2 = gc - seg * 192;
        int h = c2 >> 5, d = c2 & 31;
#pragma unroll
        for (int r = 0; r < 4; ++r) {
          int gr = m0 + wm * 32 + mt * 16 + g * 4 + r;
          int b_ = gr / 343;
          int n = gr - b_ * 343;
          dst[(((size_t)b_ * 6 + h) * 343 + n) * 32 + d] = f2b((acc[mt][nt][r] + bias) * scl);
        }
      }
    }
  }
}

// ---------------- fused attention: one block per (b,h), 8 waves x 3 row-tile passes ----------------
// launch_bounds(512,2): cap 256 unified VGPR+AGPR. (512,4) caps at 128 and SPILLS
// the st[22]/pk[22] arrays to scratch (round-2 regression: WRITE_SIZE 33->221 MB).
__global__ __launch_bounds__(512, 2) void attn_k(const u16* __restrict__ qg,
                                                 const u16* __restrict__ kg,
                                                 const u16* __restrict__ vg,
                                                 const u16* __restrict__ bias_bf,
                                                 const u64* __restrict__ mbits,
                                                 u16* __restrict__ ao) {
  __shared__ u16 ksm[352][40];  // K [kc][d], +8 pad; rows 343..351 zeroed
  __shared__ u16 vtm[32][360];  // V^T [d][kc], cols 343..359 zeroed
  const int bh = blockIdx.x;    // 0..1535
  const int b_ = bh / 6;
  const int h = bh - b_ * 6;
  const int w = b_ & 63;
  const int t = threadIdx.x;
  const int lane = t & 63;
  const int wv = t >> 6;
  const u16* kbh = kg + (size_t)bh * 10976;
  const u16* vbh = vg + (size_t)bh * 10976;
  // stage K (343 rows x 32 d), 4 float4 per row
  for (int i = t; i < 1372; i += 512) {
    float4 f = ((const float4*)kbh)[i];
    *(float4*)&ksm[i >> 2][(i & 3) * 8] = f;
  }
  if (t < 360) ksm[343 + t / 40][t % 40] = 0;  // zero K pad rows
  // stage V transposed: each lane owns a distinct column n -> write bank ~2-way
#pragma unroll
  for (int k = 0; k < 3; ++k) {
    int dq = t >> 7;                   // 0..3, uniform per wave-pair
    int n = k * 128 + (t & 127);
    if (n < 343) {
      union { float4 f4; u16 s[8]; } u;
      u.f4 = ((const float4*)vbh)[n * 4 + dq];
#pragma unroll
      for (int j = 0; j < 8; ++j) vtm[dq * 8 + j][n] = u.s[j];
    }
  }
  for (int i = t; i < 544; i += 512) vtm[i / 17][343 + i % 17] = 0;  // zero V pad cols
  __syncthreads();
  const int lr = lane & 15, g = lane >> 4;
  const f32x4_t zro = {0.f, 0.f, 0.f, 0.f};
  for (int pass = 0; pass < 3; ++pass) {
    const int rt = pass * 8 + wv;  // row-tile 0..21
    if (rt >= 22) break;
    const int q0 = rt * 16;
    const int qi = q0 + lr;
    const bool qv = qi < 343;
    const int qic = qv ? qi : 342;
    FragU qfu;
    qfu.u[0] = 0u; qfu.u[1] = 0u; qfu.u[2] = 0u; qfu.u[3] = 0u;
    if (qv) qfu.v = *(const bf16x8_t*)(qg + ((size_t)bh * 343 + qi) * 32 + g * 8);
    // S^T: st[ct][r] = S[qi][kc = ct*16 + 4*g + r]  (scale folded into q)
    f32x4_t st[22];
#pragma unroll
    for (int ct = 0; ct < 22; ++ct) {
      bf16x8_t af = *(const bf16x8_t*)&ksm[ct * 16 + lr][g * 8];
      st[ct] = __builtin_amdgcn_mfma_f32_16x16x32_bf16(af, qfu.v, zro, 0, 0, 0);
    }
    const u16* brow = bias_bf + ((size_t)h * 343 + qic) * 352;
    const u64* mrow = mbits + ((size_t)w * 343 + qic) * 6;
    u64 mw[6];
#pragma unroll
    for (int i2 = 0; i2 < 6; ++i2) mw[i2] = mrow[i2];
    float mx = 0.0f;  // max(mx,0) guard: keeps pad exp <= e^-100, softmax invariant
#pragma unroll
    for (int ct = 0; ct < 22; ++ct) {
      int kjb = ct * 16 + 4 * g;
      union { ushort4 v; u16 s[4]; } bv;
      bv.v = *(const ushort4*)&brow[kjb];
      unsigned int bits4 = (unsigned int)(mw[ct >> 2] >> ((ct & 3) * 16 + 4 * g)) & 0xFu;
#pragma unroll
      for (int r = 0; r < 4; ++r) {
        float s = st[ct][r] + b2f(bv.s[r]) + (((bits4 >> r) & 1u) ? -100.0f : 0.0f);
        st[ct][r] = s;
        mx = fmaxf(mx, s);
      }
    }
    mx = fmaxf(mx, __shfl_xor(mx, 16, 64));
    mx = fmaxf(mx, __shfl_xor(mx, 32, 64));
    float sum = 0.f;
    unsigned int pk[22][2];  // bf16-packed unnormalized P
#pragma unroll
    for (int ct = 0; ct < 22; ++ct) {
      float e0 = __expf(st[ct][0] - mx);
      float e1 = __expf(st[ct][1] - mx);
      float e2 = __expf(st[ct][2] - mx);
      float e3 = __expf(st[ct][3] - mx);
      sum += (e0 + e1) + (e2 + e3);
      pk[ct][0] = (unsigned int)f2b(e0) | ((unsigned int)f2b(e1) << 16);
      pk[ct][1] = (unsigned int)f2b(e2) | ((unsigned int)f2b(e3) << 16);
    }
    sum += __shfl_xor(sum, 16, 64);
    sum += __shfl_xor(sum, 32, 64);
    const float inv = 1.0f / sum;
    // O^T = V^T · P^T ; B-frag (P^T) gathered from pk via shuffles
    f32x4_t oa[2] = {zro, zro};
    const int base = lr + ((g & 1) << 5);
    const bool selhi = (g >> 1) != 0;
#pragma unroll
    for (int ks = 0; ks < 11; ++ks) {
      unsigned int a0 = shflu(pk[2 * ks][0], base);
      unsigned int a1 = shflu(pk[2 * ks][1], base);
      unsigned int a2 = shflu(pk[2 * ks][0], base + 16);
      unsigned int a3 = shflu(pk[2 * ks][1], base + 16);
      unsigned int c0 = shflu(pk[2 * ks + 1][0], base);
      unsigned int c1 = shflu(pk[2 * ks + 1][1], base);
      unsigned int c2 = shflu(pk[2 * ks + 1][0], base + 16);
      unsigned int c3 = shflu(pk[2 * ks + 1][1], base + 16);
      FragU bu;
      bu.u[0] = selhi ? c0 : a0;
      bu.u[1] = selhi ? c1 : a1;
      bu.u[2] = selhi ? c2 : a2;
      bu.u[3] = selhi ? c3 : a3;
#pragma unroll
      for (int mt = 0; mt < 2; ++mt) {
        bf16x8_t vf = *(const bf16x8_t*)&vtm[mt * 16 + lr][ks * 32 + g * 8];
        oa[mt] = __builtin_amdgcn_mfma_f32_16x16x32_bf16(vf, bu.v, oa[mt], 0, 0, 0);
      }
    }
    if (qv) {
      u16* orow = ao + ((size_t)b_ * 343 + qi) * 192 + h * 32;
#pragma unroll
      for (int mt = 0; mt < 2; ++mt) {
        ushort4 sv;
        sv.x = f2b(oa[mt][0] * inv);
        sv.y = f2b(oa[mt][1] * inv);
        sv.z = f2b(oa[mt][2] * inv);
        sv.w = f2b(oa[mt][3] * inv);
        *(ushort4*)&orow[mt * 16 + 4 * g] = sv;
      }
    }
  }
}

// ---------------- proj GEMM: [87808,192] bf16 x [192,192]^T + b -> fp32 out ----------------
__global__ __launch_bounds__(256) void proj_gemm(const u16* __restrict__ ao,
                                                 const u16* __restrict__ wp_bf,
                                                 const float* __restrict__ proj_b,
                                                 float* __restrict__ out) {
  __shared__ u16 as_[64][200];
  __shared__ u16 wsx[64][200];
  const int m0 = blockIdx.x * 64;
  const u16* arow = ao + (size_t)m0 * 192;
#pragma unroll
  for (int i = 0; i < 6; ++i) {
    int idx = threadIdx.x + 256 * i;
    float4 f = ((const float4*)arow)[idx];
    *(float4*)&as_[idx / 24][(idx % 24) * 8] = f;
  }
  const int lane = threadIdx.x & 63;
  const int wv = threadIdx.x >> 6;
  const int wm = wv >> 1, wn = wv & 1;
  const int lr = lane & 15, g = lane >> 4;
  const f32x4_t zro = {0.f, 0.f, 0.f, 0.f};
  for (int cseg = 0; cseg < 3; ++cseg) {
    __syncthreads();
    const u16* wrow = wp_bf + (size_t)cseg * 64 * 192;
#pragma unroll
    for (int i = 0; i < 6; ++i) {
      int idx = threadIdx.x + 256 * i;
      float4 f = ((const float4*)wrow)[idx];
      *(float4*)&wsx[idx / 24][(idx % 24) * 8] = f;
    }
    __syncthreads();
    f32x4_t acc[2][2];
    acc[0][0] = zro; acc[0][1] = zro; acc[1][0] = zro; acc[1][1] = zro;
#pragma unroll
    for (int ks = 0; ks < 6; ++ks) {
      bf16x8_t af[2], bfr[2];
#pragma unroll
      for (int t2 = 0; t2 < 2; ++t2) {
        af[t2] = *(const bf16x8_t*)&as_[wm * 32 + t2 * 16 + lr][ks * 32 + g * 8];
        bfr[t2] = *(const bf16x8_t*)&wsx[wn * 32 + t2 * 16 + lr][ks * 32 + g * 8];
      }
#pragma unroll
      for (int mt = 0; mt < 2; ++mt)
#pragma unroll
        for (int nt = 0; nt < 2; ++nt)
          acc[mt][nt] = __builtin_amdgcn_mfma_f32_16x16x32_bf16(af[mt], bfr[nt], acc[mt][nt], 0, 0, 0);
    }
    const int c0 = cseg * 64;
#pragma unroll
    for (int mt = 0; mt < 2; ++mt) {
#pragma unroll
      for (int nt = 0; nt < 2; ++nt) {
        int gc = c0 + wn * 32 + nt * 16 + lr;
        float bias = proj_b[gc];
#pragma unroll
        for (int r = 0; r < 4; ++r) {
          int gr = m0 + wm * 32 + mt * 16 + g * 4 + r;
          out[(size_t)gr * 192 + gc] = acc[mt][nt][r] + bias;
        }
      }
    }
  }
}

extern "C" void kernel_launch(void* const* d_in, const int* in_sizes, int n_in,
                              void* d_out, int out_size, void* d_ws, size_t ws_size,
                              hipStream_t stream) {
  const float* x = (const float*)d_in[0];
  const float* mask = (const float*)d_in[1];
  const float* qkv_w = (const float*)d_in[2];
  const float* qkv_b = (const float*)d_in[3];
  const float* proj_w = (const float*)d_in[4];
  const float* proj_b = (const float*)d_in[5];
  const float* bias_table = (const float*)d_in[6];
  const int* rel_index = (const int*)d_in[7];
  float* out = (float*)d_out;
  char* ws = (char*)d_ws;

  // ws layout (bytes)
  u16* qb      = (u16*)(ws + 0);          // 33,718,272
  u16* kb      = (u16*)(ws + 33718272);   // 33,718,272
  u16* vb      = (u16*)(ws + 67436544);   // 33,718,272
  u16* ao      = (u16*)(ws + 101154816);  // 33,718,272
  u16* bias_bf = (u16*)(ws + 134873088);  // 1,449,216
  u64* mbits   = (u64*)(ws + 136322304);  // 1,053,696
  u16* wq_bf   = (u16*)(ws + 137376000);  // 221,184
  u16* wp_bf   = (u16*)(ws + 137597184);  // 73,728 -> end 137,670,912

  prep_bias_k<<<2830, 256, 0, stream>>>(bias_table, rel_index, bias_bf);
  prep_maskbits_k<<<5488, 256, 0, stream>>>(mask, mbits);
  prep_w_k<<<576, 256, 0, stream>>>(qkv_w, proj_w, wq_bf, wp_bf);
  qkv_gemm<<<1372, 256, 0, stream>>>(x, wq_bf, qkv_b, qb, kb, vb);
  attn_k<<<1536, 512, 0, stream>>>(qb, kb, vb, bias_bf, mbits, ao);
  proj_gemm<<<1372, 256, 0, stream>>>(ao, wp_bf, proj_b, out);
}

// Round 4
// 216.208 us; speedup vs baseline: 1.4818x; 1.0544x over previous
//
#include <hip/hip_runtime.h>

typedef __bf16 bf16x8_t __attribute__((ext_vector_type(8)));
typedef float f32x4_t __attribute__((ext_vector_type(4)));
typedef short s16x4 __attribute__((ext_vector_type(4)));
typedef unsigned short u16;
typedef unsigned long long u64;

__device__ __forceinline__ u16 f2b(float f) {
  __bf16 h = (__bf16)f;
  u16 u;
  __builtin_memcpy(&u, &h, 2);
  return u;
}
__device__ __forceinline__ float b2f(u16 u) {
  unsigned int i = ((unsigned int)u) << 16;
  float f;
  __builtin_memcpy(&f, &i, 4);
  return f;
}

union FragU { unsigned int u[4]; bf16x8_t v; };
union PkU { unsigned int u[2]; s16x4 v; };

// ---------------- prep: bias gather -> bf16 [6][343][352], pad cols zeroed ----------------
__global__ void prep_bias_k(const float* __restrict__ bias_table,
                            const int* __restrict__ rel_index,
                            u16* __restrict__ bias_bf) {
  int i = blockIdx.x * 256 + threadIdx.x;
  if (i >= 6 * 343 * 352) return;
  int h = i / (343 * 352);
  int rem = i - h * (343 * 352);
  int r = rem / 352;
  int c = rem - r * 352;
  u16 val = 0;
  if (c < 343) {
    int idx = rel_index[r * 343 + c];
    val = f2b(bias_table[idx * 6 + h]);
  }
  bias_bf[((size_t)h * 343 + r) * 352 + c] = val;
}

// ---------------- prep: mask -> bit table [64*343][6] u64 (bit=1 means masked) ----------------
__global__ void prep_maskbits_k(const float* __restrict__ mask, u64* __restrict__ mbits) {
  int row = blockIdx.x * 4 + (threadIdx.x >> 6);  // 0..21951
  int lane = threadIdx.x & 63;
  const float* mrow = mask + (size_t)row * 343;
#pragma unroll
  for (int it = 0; it < 6; ++it) {
    int idx = it * 64 + lane;
    float v = (idx < 343) ? mrow[idx] : -100.0f;  // pad cols masked
    u64 b = __ballot(v < -50.0f);
    if (lane == 0) mbits[(size_t)row * 6 + it] = b;
  }
}

// ---------------- prep: weights fp32 -> bf16 ----------------
__global__ void prep_w_k(const float* __restrict__ qkv_w, const float* __restrict__ proj_w,
                         u16* __restrict__ wq, u16* __restrict__ wp) {
  int i = blockIdx.x * 256 + threadIdx.x;
  if (i < 110592) wq[i] = f2b(qkv_w[i]);
  int j = i - 110592;
  if (j >= 0 && j < 36864) wp[j] = f2b(proj_w[j]);
}

// ---------------- QKV GEMM: [87808,192] x [576,192]^T -> q,k,v bf16 [b,h,n,32] ----------------
__global__ __launch_bounds__(256) void qkv_gemm(const float* __restrict__ x,
                                                const u16* __restrict__ w_bf,
                                                const float* __restrict__ qkv_b,
                                                u16* __restrict__ qb,
                                                u16* __restrict__ kb,
                                                u16* __restrict__ vb) {
  __shared__ u16 xs[64][200];   // +8 pad
  __shared__ u16 wsx[64][200];
  const int m0 = blockIdx.x * 64;
  const float* xrow = x + (size_t)m0 * 192;
#pragma unroll
  for (int i = 0; i < 12; ++i) {
    int idx = threadIdx.x + 256 * i;
    float4 f = ((const float4*)xrow)[idx];
    int r = idx / 48, k4 = (idx % 48) * 4;
    ushort4 a;
    a.x = f2b(f.x); a.y = f2b(f.y); a.z = f2b(f.z); a.w = f2b(f.w);
    *(ushort4*)&xs[r][k4] = a;
  }
  const int lane = threadIdx.x & 63;
  const int wv = threadIdx.x >> 6;
  const int wm = wv >> 1, wn = wv & 1;
  const int lr = lane & 15, g = lane >> 4;
  const f32x4_t zro = {0.f, 0.f, 0.f, 0.f};
  for (int cseg = 0; cseg < 9; ++cseg) {
    __syncthreads();
    const u16* wrow = w_bf + (size_t)cseg * 64 * 192;
#pragma unroll
    for (int i = 0; i < 6; ++i) {
      int idx = threadIdx.x + 256 * i;  // 16B chunks
      float4 f = ((const float4*)wrow)[idx];
      *(float4*)&wsx[idx / 24][(idx % 24) * 8] = f;
    }
    __syncthreads();
    f32x4_t acc[2][2];
    acc[0][0] = zro; acc[0][1] = zro; acc[1][0] = zro; acc[1][1] = zro;
#pragma unroll
    for (int ks = 0; ks < 6; ++ks) {
      bf16x8_t af[2], bfr[2];
#pragma unroll
      for (int t2 = 0; t2 < 2; ++t2) {
        af[t2] = *(const bf16x8_t*)&xs[wm * 32 + t2 * 16 + lr][ks * 32 + g * 8];
        bfr[t2] = *(const bf16x8_t*)&wsx[wn * 32 + t2 * 16 + lr][ks * 32 + g * 8];
      }
#pragma unroll
      for (int mt = 0; mt < 2; ++mt)
#pragma unroll
        for (int nt = 0; nt < 2; ++nt)
          acc[mt][nt] = __builtin_amdgcn_mfma_f32_16x16x32_bf16(af[mt], bfr[nt], acc[mt][nt], 0, 0, 0);
    }
    const int c0 = cseg * 64;
    const int seg = c0 / 192;  // 0=q 1=k 2=v
    u16* dst = (seg == 0) ? qb : ((seg == 1) ? kb : vb);
    const float scl = (seg == 0) ? 0.17677669529663687f : 1.0f;
#pragma unroll
    for (int mt = 0; mt < 2; ++mt) {
#pragma unroll
      for (int nt = 0; nt < 2; ++nt) {
        int gc = c0 + wn * 32 + nt * 16 + lr;
        float bias = qkv_b[gc];
        int c2 = gc - seg * 192;
        int h = c2 >> 5, d = c2 & 31;
#pragma unroll
        for (int r = 0; r < 4; ++r) {
          int gr = m0 + wm * 32 + mt * 16 + g * 4 + r;
          int b_ = gr / 343;
          int n = gr - b_ * 343;
          dst[(((size_t)b_ * 6 + h) * 343 + n) * 32 + d] = f2b((acc[mt][nt][r] + bias) * scl);
        }
      }
    }
  }
}

// ---------------- fused attention: one block per (b,h), 8 waves x 3 row-tile passes ----------------
// launch_bounds(512,2): cap 256 unified VGPR+AGPR. (512,4) caps at 128 and SPILLS
// st[22]/pk[22] to scratch (round-2 regression: WRITE_SIZE 33->221 MB).
// PV uses mfma_f32_16x16x16 (K=16): B-frag layout (lane: col=l&15, k=(l>>4)*4+j)
// EXACTLY matches where swapped-QK^T leaves P in registers -> zero shuffles.
__global__ __launch_bounds__(512, 2) void attn_k(const u16* __restrict__ qg,
                                                 const u16* __restrict__ kg,
                                                 const u16* __restrict__ vg,
                                                 const u16* __restrict__ bias_bf,
                                                 const u64* __restrict__ mbits,
                                                 u16* __restrict__ ao) {
  __shared__ u16 ksm[352][40];   // K [kc][d], +8 pad; rows 343..351 zeroed
  __shared__ u16 vtm[32][372];   // V^T [d][kc], stride 372 -> 8B frag reads 2-way (free)
  const int bh = blockIdx.x;    // 0..1535
  const int b_ = bh / 6;
  const int h = bh - b_ * 6;
  const int w = b_ & 63;
  const int t = threadIdx.x;
  const int lane = t & 63;
  const int wv = t >> 6;
  const u16* kbh = kg + (size_t)bh * 10976;
  const u16* vbh = vg + (size_t)bh * 10976;
  // stage K (343 rows x 32 d), 4 float4 per row
  for (int i = t; i < 1372; i += 512) {
    float4 f = ((const float4*)kbh)[i];
    *(float4*)&ksm[i >> 2][(i & 3) * 8] = f;
  }
  if (t < 360) ksm[343 + t / 40][t % 40] = 0;  // zero K pad rows
  // stage V transposed: each lane owns a distinct column n -> write ~2-way
#pragma unroll
  for (int k = 0; k < 3; ++k) {
    int dq = t >> 7;                   // 0..3, uniform per wave-pair
    int n = k * 128 + (t & 127);
    if (n < 343) {
      union { float4 f4; u16 s[8]; } u;
      u.f4 = ((const float4*)vbh)[n * 4 + dq];
#pragma unroll
      for (int j = 0; j < 8; ++j) vtm[dq * 8 + j][n] = u.s[j];
    }
  }
  for (int i = t; i < 928; i += 512) vtm[i / 29][343 + i % 29] = 0;  // zero V pad cols
  __syncthreads();
  const int lr = lane & 15, g = lane >> 4;
  const f32x4_t zro = {0.f, 0.f, 0.f, 0.f};
  for (int pass = 0; pass < 3; ++pass) {
    const int rt = pass * 8 + wv;  // row-tile 0..21
    if (rt >= 22) break;
    const int q0 = rt * 16;
    const int qi = q0 + lr;
    const bool qv = qi < 343;
    const int qic = qv ? qi : 342;
    FragU qfu;
    qfu.u[0] = 0u; qfu.u[1] = 0u; qfu.u[2] = 0u; qfu.u[3] = 0u;
    if (qv) qfu.v = *(const bf16x8_t*)(qg + ((size_t)bh * 343 + qi) * 32 + g * 8);
    // S^T: st[ct][r] = S[qi][kc = ct*16 + 4*g + r]  (scale folded into q)
    f32x4_t st[22];
#pragma unroll
    for (int ct = 0; ct < 22; ++ct) {
      bf16x8_t af = *(const bf16x8_t*)&ksm[ct * 16 + lr][g * 8];
      st[ct] = __builtin_amdgcn_mfma_f32_16x16x32_bf16(af, qfu.v, zro, 0, 0, 0);
    }
    const u16* brow = bias_bf + ((size_t)h * 343 + qic) * 352;
    const u64* mrow = mbits + ((size_t)w * 343 + qic) * 6;
    u64 mw[6];
#pragma unroll
    for (int i2 = 0; i2 < 6; ++i2) mw[i2] = mrow[i2];
    float mx = 0.0f;  // max(mx,0) guard: keeps pad exp <= e^-100 ~ 0, softmax invariant
#pragma unroll
    for (int ct = 0; ct < 22; ++ct) {
      int kjb = ct * 16 + 4 * g;
      union { ushort4 v; u16 s[4]; } bv;
      bv.v = *(const ushort4*)&brow[kjb];
      unsigned int bits4 = (unsigned int)(mw[ct >> 2] >> ((ct & 3) * 16 + 4 * g)) & 0xFu;
#pragma unroll
      for (int r = 0; r < 4; ++r) {
        float s = st[ct][r] + b2f(bv.s[r]) + (((bits4 >> r) & 1u) ? -100.0f : 0.0f);
        st[ct][r] = s;
        mx = fmaxf(mx, s);
      }
    }
    mx = fmaxf(mx, __shfl_xor(mx, 16, 64));
    mx = fmaxf(mx, __shfl_xor(mx, 32, 64));
    float sum = 0.f;
    PkU pk[22];  // bf16-packed unnormalized P, B-frag-ready
#pragma unroll
    for (int ct = 0; ct < 22; ++ct) {
      float e0 = __expf(st[ct][0] - mx);
      float e1 = __expf(st[ct][1] - mx);
      float e2 = __expf(st[ct][2] - mx);
      float e3 = __expf(st[ct][3] - mx);
      sum += (e0 + e1) + (e2 + e3);
      pk[ct].u[0] = (unsigned int)f2b(e0) | ((unsigned int)f2b(e1) << 16);
      pk[ct].u[1] = (unsigned int)f2b(e2) | ((unsigned int)f2b(e3) << 16);
    }
    sum += __shfl_xor(sum, 16, 64);
    sum += __shfl_xor(sum, 32, 64);
    const float inv = 1.0f / sum;
    // O^T = V^T · P^T via 16x16x16 MFMA; pk[ct] IS the B-fragment for k-tile ct.
    f32x4_t oa[2] = {zro, zro};
#pragma unroll
    for (int ct = 0; ct < 22; ++ct) {
      s16x4 bfrag = pk[ct].v;
#pragma unroll
      for (int mt = 0; mt < 2; ++mt) {
        s16x4 af = *(const s16x4*)&vtm[mt * 16 + lr][ct * 16 + g * 4];
        oa[mt] = __builtin_amdgcn_mfma_f32_16x16x16bf16_1k(af, bfrag, oa[mt], 0, 0, 0);
      }
    }
    if (qv) {
      u16* orow = ao + ((size_t)b_ * 343 + qi) * 192 + h * 32;
#pragma unroll
      for (int mt = 0; mt < 2; ++mt) {
        ushort4 sv;
        sv.x = f2b(oa[mt][0] * inv);
        sv.y = f2b(oa[mt][1] * inv);
        sv.z = f2b(oa[mt][2] * inv);
        sv.w = f2b(oa[mt][3] * inv);
        *(ushort4*)&orow[mt * 16 + 4 * g] = sv;
      }
    }
  }
}

// ---------------- proj GEMM: [87808,192] bf16 x [192,192]^T + b -> fp32 out ----------------
__global__ __launch_bounds__(256) void proj_gemm(const u16* __restrict__ ao,
                                                 const u16* __restrict__ wp_bf,
                                                 const float* __restrict__ proj_b,
                                                 float* __restrict__ out) {
  __shared__ u16 as_[64][200];
  __shared__ u16 wsx[64][200];
  const int m0 = blockIdx.x * 64;
  const u16* arow = ao + (size_t)m0 * 192;
#pragma unroll
  for (int i = 0; i < 6; ++i) {
    int idx = threadIdx.x + 256 * i;
    float4 f = ((const float4*)arow)[idx];
    *(float4*)&as_[idx / 24][(idx % 24) * 8] = f;
  }
  const int lane = threadIdx.x & 63;
  const int wv = threadIdx.x >> 6;
  const int wm = wv >> 1, wn = wv & 1;
  const int lr = lane & 15, g = lane >> 4;
  const f32x4_t zro = {0.f, 0.f, 0.f, 0.f};
  for (int cseg = 0; cseg < 3; ++cseg) {
    __syncthreads();
    const u16* wrow = wp_bf + (size_t)cseg * 64 * 192;
#pragma unroll
    for (int i = 0; i < 6; ++i) {
      int idx = threadIdx.x + 256 * i;
      float4 f = ((const float4*)wrow)[idx];
      *(float4*)&wsx[idx / 24][(idx % 24) * 8] = f;
    }
    __syncthreads();
    f32x4_t acc[2][2];
    acc[0][0] = zro; acc[0][1] = zro; acc[1][0] = zro; acc[1][1] = zro;
#pragma unroll
    for (int ks = 0; ks < 6; ++ks) {
      bf16x8_t af[2], bfr[2];
#pragma unroll
      for (int t2 = 0; t2 < 2; ++t2) {
        af[t2] = *(const bf16x8_t*)&as_[wm * 32 + t2 * 16 + lr][ks * 32 + g * 8];
        bfr[t2] = *(const bf16x8_t*)&wsx[wn * 32 + t2 * 16 + lr][ks * 32 + g * 8];
      }
#pragma unroll
      for (int mt = 0; mt < 2; ++mt)
#pragma unroll
        for (int nt = 0; nt < 2; ++nt)
          acc[mt][nt] = __builtin_amdgcn_mfma_f32_16x16x32_bf16(af[mt], bfr[nt], acc[mt][nt], 0, 0, 0);
    }
    const int c0 = cseg * 64;
#pragma unroll
    for (int mt = 0; mt < 2; ++mt) {
#pragma unroll
      for (int nt = 0; nt < 2; ++nt) {
        int gc = c0 + wn * 32 + nt * 16 + lr;
        float bias = proj_b[gc];
#pragma unroll
        for (int r = 0; r < 4; ++r) {
          int gr = m0 + wm * 32 + mt * 16 + g * 4 + r;
          out[(size_t)gr * 192 + gc] = acc[mt][nt][r] + bias;
        }
      }
    }
  }
}

extern "C" void kernel_launch(void* const* d_in, const int* in_sizes, int n_in,
                              void* d_out, int out_size, void* d_ws, size_t ws_size,
                              hipStream_t stream) {
  const float* x = (const float*)d_in[0];
  const float* mask = (const float*)d_in[1];
  const float* qkv_w = (const float*)d_in[2];
  const float* qkv_b = (const float*)d_in[3];
  const float* proj_w = (const float*)d_in[4];
  const float* proj_b = (const float*)d_in[5];
  const float* bias_table = (const float*)d_in[6];
  const int* rel_index = (const int*)d_in[7];
  float* out = (float*)d_out;
  char* ws = (char*)d_ws;

  // ws layout (bytes)
  u16* qb      = (u16*)(ws + 0);          // 33,718,272
  u16* kb      = (u16*)(ws + 33718272);   // 33,718,272
  u16* vb      = (u16*)(ws + 67436544);   // 33,718,272
  u16* ao      = (u16*)(ws + 101154816);  // 33,718,272
  u16* bias_bf = (u16*)(ws + 134873088);  // 1,449,216
  u64* mbits   = (u64*)(ws + 136322304);  // 1,053,696
  u16* wq_bf   = (u16*)(ws + 137376000);  // 221,184
  u16* wp_bf   = (u16*)(ws + 137597184);  // 73,728 -> end 137,670,912

  prep_bias_k<<<2830, 256, 0, stream>>>(bias_table, rel_index, bias_bf);
  prep_maskbits_k<<<5488, 256, 0, stream>>>(mask, mbits);
  prep_w_k<<<576, 256, 0, stream>>>(qkv_w, proj_w, wq_bf, wp_bf);
  qkv_gemm<<<1372, 256, 0, stream>>>(x, wq_bf, qkv_b, qb, kb, vb);
  attn_k<<<1536, 512, 0, stream>>>(qb, kb, vb, bias_bf, mbits, ao);
  proj_gemm<<<1372, 256, 0, stream>>>(ao, wp_bf, proj_b, out);
}

// Round 5
// 175.937 us; speedup vs baseline: 1.8210x; 1.2289x over previous
//
#include <hip/hip_runtime.h>

typedef __bf16 bf16x8_t __attribute__((ext_vector_type(8)));
typedef float f32x4_t __attribute__((ext_vector_type(4)));
typedef short s16x4 __attribute__((ext_vector_type(4)));
typedef unsigned short u16;
typedef unsigned long long u64;

__device__ __forceinline__ u16 f2b(float f) {
  __bf16 h = (__bf16)f;
  u16 u;
  __builtin_memcpy(&u, &h, 2);
  return u;
}
__device__ __forceinline__ float b2f(u16 u) {
  unsigned int i = ((unsigned int)u) << 16;
  float f;
  __builtin_memcpy(&f, &i, 4);
  return f;
}

union FragU { unsigned int u[4]; bf16x8_t v; };
union PkU { unsigned int u[2]; s16x4 v; };

// ---------------- prep: bias gather -> bf16 [6][343][352] SCALED BY log2(e) ----------------
// (softmax computed as exp2((qk*scale + bias + mask)*log2e) with log2e folded into
//  q-scale, bias table, and the mask constant; no max-subtraction — logits are O(1)
//  by construction and exp(s)/sum == exp(s-m)/sum exactly.)
__global__ void prep_bias_k(const float* __restrict__ bias_table,
                            const int* __restrict__ rel_index,
                            u16* __restrict__ bias_bf) {
  int i = blockIdx.x * 256 + threadIdx.x;
  if (i >= 6 * 343 * 352) return;
  int h = i / (343 * 352);
  int rem = i - h * (343 * 352);
  int r = rem / 352;
  int c = rem - r * 352;
  u16 val = 0;
  if (c < 343) {
    int idx = rel_index[r * 343 + c];
    val = f2b(bias_table[idx * 6 + h] * 1.4426950408889634f);
  }
  bias_bf[((size_t)h * 343 + r) * 352 + c] = val;
}

// ---------------- prep: mask -> bit table [64*343][6] u64 (bit=1 means masked) ----------------
__global__ void prep_maskbits_k(const float* __restrict__ mask, u64* __restrict__ mbits) {
  int row = blockIdx.x * 4 + (threadIdx.x >> 6);  // 0..21951
  int lane = threadIdx.x & 63;
  const float* mrow = mask + (size_t)row * 343;
#pragma unroll
  for (int it = 0; it < 6; ++it) {
    int idx = it * 64 + lane;
    float v = (idx < 343) ? mrow[idx] : -100.0f;  // pad cols masked
    u64 b = __ballot(v < -50.0f);
    if (lane == 0) mbits[(size_t)row * 6 + it] = b;
  }
}

// ---------------- prep: weights fp32 -> bf16 ----------------
__global__ void prep_w_k(const float* __restrict__ qkv_w, const float* __restrict__ proj_w,
                         u16* __restrict__ wq, u16* __restrict__ wp) {
  int i = blockIdx.x * 256 + threadIdx.x;
  if (i < 110592) wq[i] = f2b(qkv_w[i]);
  int j = i - 110592;
  if (j >= 0 && j < 36864) wp[j] = f2b(proj_w[j]);
}

// ---------------- QKV GEMM: [87808,192] x [576,192]^T -> q,k,v bf16 [b,h,n,32] ----------------
__global__ __launch_bounds__(256) void qkv_gemm(const float* __restrict__ x,
                                                const u16* __restrict__ w_bf,
                                                const float* __restrict__ qkv_b,
                                                u16* __restrict__ qb,
                                                u16* __restrict__ kb,
                                                u16* __restrict__ vb) {
  __shared__ u16 xs[64][200];   // +8 pad
  __shared__ u16 wsx[64][200];
  const int m0 = blockIdx.x * 64;
  const float* xrow = x + (size_t)m0 * 192;
#pragma unroll
  for (int i = 0; i < 12; ++i) {
    int idx = threadIdx.x + 256 * i;
    float4 f = ((const float4*)xrow)[idx];
    int r = idx / 48, k4 = (idx % 48) * 4;
    ushort4 a;
    a.x = f2b(f.x); a.y = f2b(f.y); a.z = f2b(f.z); a.w = f2b(f.w);
    *(ushort4*)&xs[r][k4] = a;
  }
  const int lane = threadIdx.x & 63;
  const int wv = threadIdx.x >> 6;
  const int wm = wv >> 1, wn = wv & 1;
  const int lr = lane & 15, g = lane >> 4;
  const f32x4_t zro = {0.f, 0.f, 0.f, 0.f};
  for (int cseg = 0; cseg < 9; ++cseg) {
    __syncthreads();
    const u16* wrow = w_bf + (size_t)cseg * 64 * 192;
#pragma unroll
    for (int i = 0; i < 6; ++i) {
      int idx = threadIdx.x + 256 * i;  // 16B chunks
      float4 f = ((const float4*)wrow)[idx];
      *(float4*)&wsx[idx / 24][(idx % 24) * 8] = f;
    }
    __syncthreads();
    f32x4_t acc[2][2];
    acc[0][0] = zro; acc[0][1] = zro; acc[1][0] = zro; acc[1][1] = zro;
#pragma unroll
    for (int ks = 0; ks < 6; ++ks) {
      bf16x8_t af[2], bfr[2];
#pragma unroll
      for (int t2 = 0; t2 < 2; ++t2) {
        af[t2] = *(const bf16x8_t*)&xs[wm * 32 + t2 * 16 + lr][ks * 32 + g * 8];
        bfr[t2] = *(const bf16x8_t*)&wsx[wn * 32 + t2 * 16 + lr][ks * 32 + g * 8];
      }
#pragma unroll
      for (int mt = 0; mt < 2; ++mt)
#pragma unroll
        for (int nt = 0; nt < 2; ++nt)
          acc[mt][nt] = __builtin_amdgcn_mfma_f32_16x16x32_bf16(af[mt], bfr[nt], acc[mt][nt], 0, 0, 0);
    }
    const int c0 = cseg * 64;
    const int seg = c0 / 192;  // 0=q 1=k 2=v
    u16* dst = (seg == 0) ? qb : ((seg == 1) ? kb : vb);
    // q gets attention scale AND log2(e) folded in (exp2-based softmax downstream)
    const float scl = (seg == 0) ? (0.17677669529663687f * 1.4426950408889634f) : 1.0f;
#pragma unroll
    for (int mt = 0; mt < 2; ++mt) {
#pragma unroll
      for (int nt = 0; nt < 2; ++nt) {
        int gc = c0 + wn * 32 + nt * 16 + lr;
        float bias = qkv_b[gc];
        int c2 = gc - seg * 192;
        int h = c2 >> 5, d = c2 & 31;
#pragma unroll
        for (int r = 0; r < 4; ++r) {
          int gr = m0 + wm * 32 + mt * 16 + g * 4 + r;
          int b_ = gr / 343;
          int n = gr - b_ * 343;
          dst[(((size_t)b_ * 6 + h) * 343 + n) * 32 + d] = f2b((acc[mt][nt][r] + bias) * scl);
        }
      }
    }
  }
}

// ---------------- fused attention: one block per (b,h), 8 waves x 3 row-tile passes ----------------
// launch_bounds(512,2): cap 256 unified VGPR+AGPR. (512,4) caps at 128 and SPILLED in R2.
// Softmax is single-sweep: QK^T MFMA -> +bias +mask -> exp2 -> pack, no max pass
// (logits O(1); exp(s)/sum == exp(s-m)/sum). st[22] array eliminated (-88 live VGPRs).
// PV uses mfma 16x16x16: B-frag layout matches where swapped-QK^T leaves P -> zero shuffles.
__global__ __launch_bounds__(512, 2) void attn_k(const u16* __restrict__ qg,
                                                 const u16* __restrict__ kg,
                                                 const u16* __restrict__ vg,
                                                 const u16* __restrict__ bias_bf,
                                                 const u64* __restrict__ mbits,
                                                 u16* __restrict__ ao) {
  __shared__ u16 ksm[352][40];   // K [kc][d], +8 pad; rows 343..351 zeroed
  __shared__ u16 vtm[32][372];   // V^T [d][kc], stride 372 -> 8B frag reads 2-way (free)
  const int bh = blockIdx.x;    // 0..1535
  const int b_ = bh / 6;
  const int h = bh - b_ * 6;
  const int w = b_ & 63;
  const int t = threadIdx.x;
  const int lane = t & 63;
  const int wv = t >> 6;
  const u16* kbh = kg + (size_t)bh * 10976;
  const u16* vbh = vg + (size_t)bh * 10976;
  // stage K (343 rows x 32 d), 4 float4 per row
  for (int i = t; i < 1372; i += 512) {
    float4 f = ((const float4*)kbh)[i];
    *(float4*)&ksm[i >> 2][(i & 3) * 8] = f;
  }
  if (t < 360) ksm[343 + t / 40][t % 40] = 0;  // zero K pad rows
  // stage V transposed: each lane owns a distinct column n -> write ~2-way
#pragma unroll
  for (int k = 0; k < 3; ++k) {
    int dq = t >> 7;                   // 0..3, uniform per wave-pair
    int n = k * 128 + (t & 127);
    if (n < 343) {
      union { float4 f4; u16 s[8]; } u;
      u.f4 = ((const float4*)vbh)[n * 4 + dq];
#pragma unroll
      for (int j = 0; j < 8; ++j) vtm[dq * 8 + j][n] = u.s[j];
    }
  }
  for (int i = t; i < 928; i += 512) vtm[i / 29][343 + i % 29] = 0;  // zero V pad cols
  __syncthreads();
  const int lr = lane & 15, g = lane >> 4;
  const f32x4_t zro = {0.f, 0.f, 0.f, 0.f};
  for (int pass = 0; pass < 3; ++pass) {
    const int rt = pass * 8 + wv;  // row-tile 0..21
    if (rt >= 22) break;
    const int q0 = rt * 16;
    const int qi = q0 + lr;
    const bool qv = qi < 343;
    const int qic = qv ? qi : 342;
    FragU qfu;
    qfu.u[0] = 0u; qfu.u[1] = 0u; qfu.u[2] = 0u; qfu.u[3] = 0u;
    if (qv) qfu.v = *(const bf16x8_t*)(qg + ((size_t)bh * 343 + qi) * 32 + g * 8);
    const u16* brow = bias_bf + ((size_t)h * 343 + qic) * 352;
    const u64* mrow = mbits + ((size_t)w * 343 + qic) * 6;
    u64 mw[6];
#pragma unroll
    for (int i2 = 0; i2 < 6; ++i2) mw[i2] = mrow[i2];
    // single fused sweep: S^T tile -> bias+mask -> exp2 -> bf16 pack (B-frag-ready)
    float sum = 0.f;
    PkU pk[22];
#pragma unroll
    for (int ct = 0; ct < 22; ++ct) {
      bf16x8_t af = *(const bf16x8_t*)&ksm[ct * 16 + lr][g * 8];
      f32x4_t s4 = __builtin_amdgcn_mfma_f32_16x16x32_bf16(af, qfu.v, zro, 0, 0, 0);
      int kjb = ct * 16 + 4 * g;
      union { ushort4 v; u16 s[4]; } bv;
      bv.v = *(const ushort4*)&brow[kjb];
      unsigned int bits4 = (unsigned int)(mw[ct >> 2] >> ((ct & 3) * 16 + 4 * g)) & 0xFu;
      float e0, e1, e2, e3;
      {
        float s0 = s4[0] + b2f(bv.s[0]) + (((bits4 >> 0) & 1u) ? -144.26950408889634f : 0.0f);
        float s1 = s4[1] + b2f(bv.s[1]) + (((bits4 >> 1) & 1u) ? -144.26950408889634f : 0.0f);
        float s2 = s4[2] + b2f(bv.s[2]) + (((bits4 >> 2) & 1u) ? -144.26950408889634f : 0.0f);
        float s3 = s4[3] + b2f(bv.s[3]) + (((bits4 >> 3) & 1u) ? -144.26950408889634f : 0.0f);
        e0 = __builtin_amdgcn_exp2f(s0);
        e1 = __builtin_amdgcn_exp2f(s1);
        e2 = __builtin_amdgcn_exp2f(s2);
        e3 = __builtin_amdgcn_exp2f(s3);
      }
      sum += (e0 + e1) + (e2 + e3);
      pk[ct].u[0] = (unsigned int)f2b(e0) | ((unsigned int)f2b(e1) << 16);
      pk[ct].u[1] = (unsigned int)f2b(e2) | ((unsigned int)f2b(e3) << 16);
    }
    sum += __shfl_xor(sum, 16, 64);
    sum += __shfl_xor(sum, 32, 64);
    const float inv = 1.0f / sum;
    // O^T = V^T · P^T via 16x16x16 MFMA; pk[ct] IS the B-fragment for k-tile ct.
    f32x4_t oa[2] = {zro, zro};
#pragma unroll
    for (int ct = 0; ct < 22; ++ct) {
      s16x4 bfrag = pk[ct].v;
#pragma unroll
      for (int mt = 0; mt < 2; ++mt) {
        s16x4 af = *(const s16x4*)&vtm[mt * 16 + lr][ct * 16 + g * 4];
        oa[mt] = __builtin_amdgcn_mfma_f32_16x16x16bf16_1k(af, bfrag, oa[mt], 0, 0, 0);
      }
    }
    if (qv) {
      u16* orow = ao + ((size_t)b_ * 343 + qi) * 192 + h * 32;
#pragma unroll
      for (int mt = 0; mt < 2; ++mt) {
        ushort4 sv;
        sv.x = f2b(oa[mt][0] * inv);
        sv.y = f2b(oa[mt][1] * inv);
        sv.z = f2b(oa[mt][2] * inv);
        sv.w = f2b(oa[mt][3] * inv);
        *(ushort4*)&orow[mt * 16 + 4 * g] = sv;
      }
    }
  }
}

// ---------------- proj GEMM: [87808,192] bf16 x [192,192]^T + b -> fp32 out ----------------
__global__ __launch_bounds__(256) void proj_gemm(const u16* __restrict__ ao,
                                                 const u16* __restrict__ wp_bf,
                                                 const float* __restrict__ proj_b,
                                                 float* __restrict__ out) {
  __shared__ u16 as_[64][200];
  __shared__ u16 wsx[64][200];
  const int m0 = blockIdx.x * 64;
  const u16* arow = ao + (size_t)m0 * 192;
#pragma unroll
  for (int i = 0; i < 6; ++i) {
    int idx = threadIdx.x + 256 * i;
    float4 f = ((const float4*)arow)[idx];
    *(float4*)&as_[idx / 24][(idx % 24) * 8] = f;
  }
  const int lane = threadIdx.x & 63;
  const int wv = threadIdx.x >> 6;
  const int wm = wv >> 1, wn = wv & 1;
  const int lr = lane & 15, g = lane >> 4;
  const f32x4_t zro = {0.f, 0.f, 0.f, 0.f};
  for (int cseg = 0; cseg < 3; ++cseg) {
    __syncthreads();
    const u16* wrow = wp_bf + (size_t)cseg * 64 * 192;
#pragma unroll
    for (int i = 0; i < 6; ++i) {
      int idx = threadIdx.x + 256 * i;
      float4 f = ((const float4*)wrow)[idx];
      *(float4*)&wsx[idx / 24][(idx % 24) * 8] = f;
    }
    __syncthreads();
    f32x4_t acc[2][2];
    acc[0][0] = zro; acc[0][1] = zro; acc[1][0] = zro; acc[1][1] = zro;
#pragma unroll
    for (int ks = 0; ks < 6; ++ks) {
      bf16x8_t af[2], bfr[2];
#pragma unroll
      for (int t2 = 0; t2 < 2; ++t2) {
        af[t2] = *(const bf16x8_t*)&as_[wm * 32 + t2 * 16 + lr][ks * 32 + g * 8];
        bfr[t2] = *(const bf16x8_t*)&wsx[wn * 32 + t2 * 16 + lr][ks * 32 + g * 8];
      }
#pragma unroll
      for (int mt = 0; mt < 2; ++mt)
#pragma unroll
        for (int nt = 0; nt < 2; ++nt)
          acc[mt][nt] = __builtin_amdgcn_mfma_f32_16x16x32_bf16(af[mt], bfr[nt], acc[mt][nt], 0, 0, 0);
    }
    const int c0 = cseg * 64;
#pragma unroll
    for (int mt = 0; mt < 2; ++mt) {
#pragma unroll
      for (int nt = 0; nt < 2; ++nt) {
        int gc = c0 + wn * 32 + nt * 16 + lr;
        float bias = proj_b[gc];
#pragma unroll
        for (int r = 0; r < 4; ++r) {
          int gr = m0 + wm * 32 + mt * 16 + g * 4 + r;
          out[(size_t)gr * 192 + gc] = acc[mt][nt][r] + bias;
        }
      }
    }
  }
}

extern "C" void kernel_launch(void* const* d_in, const int* in_sizes, int n_in,
                              void* d_out, int out_size, void* d_ws, size_t ws_size,
                              hipStream_t stream) {
  const float* x = (const float*)d_in[0];
  const float* mask = (const float*)d_in[1];
  const float* qkv_w = (const float*)d_in[2];
  const float* qkv_b = (const float*)d_in[3];
  const float* proj_w = (const float*)d_in[4];
  const float* proj_b = (const float*)d_in[5];
  const float* bias_table = (const float*)d_in[6];
  const int* rel_index = (const int*)d_in[7];
  float* out = (float*)d_out;
  char* ws = (char*)d_ws;

  // ws layout (bytes)
  u16* qb      = (u16*)(ws + 0);          // 33,718,272
  u16* kb      = (u16*)(ws + 33718272);   // 33,718,272
  u16* vb      = (u16*)(ws + 67436544);   // 33,718,272
  u16* ao      = (u16*)(ws + 101154816);  // 33,718,272
  u16* bias_bf = (u16*)(ws + 134873088);  // 1,449,216
  u64* mbits   = (u64*)(ws + 136322304);  // 1,053,696
  u16* wq_bf   = (u16*)(ws + 137376000);  // 221,184
  u16* wp_bf   = (u16*)(ws + 137597184);  // 73,728 -> end 137,670,912

  prep_bias_k<<<2830, 256, 0, stream>>>(bias_table, rel_index, bias_bf);
  prep_maskbits_k<<<5488, 256, 0, stream>>>(mask, mbits);
  prep_w_k<<<576, 256, 0, stream>>>(qkv_w, proj_w, wq_bf, wp_bf);
  qkv_gemm<<<1372, 256, 0, stream>>>(x, wq_bf, qkv_b, qb, kb, vb);
  attn_k<<<1536, 512, 0, stream>>>(qb, kb, vb, bias_bf, mbits, ao);
  proj_gemm<<<1372, 256, 0, stream>>>(ao, wp_bf, proj_b, out);
}